// Round 1
// baseline (379.434 us; speedup 1.0000x reference)
//
#include <hip/hip_runtime.h>
#include <hip/hip_bf16.h>
#include <math.h>

// Problem constants (T=2048, B=2, C=1024, H=16, DK=64)
#define T_SEQ 2048
#define B_SZ 2
#define C_DIM 1024
#define H_HEADS 16
#define DKH 64
#define M_ROWS (T_SEQ * B_SZ)   // 4096 rows in (t,b) order — matches [T,B,C] flat layout

typedef __attribute__((ext_vector_type(8))) short bf16x8;   // 8 bf16 = 4 VGPRs (MFMA A/B frag)
typedef __attribute__((ext_vector_type(4))) float f32x4;    // MFMA C/D frag
typedef unsigned short ushort_t;

// ---- helpers ----------------------------------------------------------------

// fp32 -> bf16 round-to-nearest-even, branch-free
__device__ __forceinline__ ushort_t f2bf(float f) {
    unsigned u = __float_as_uint(f);
    u += 0x7fffu + ((u >> 16) & 1u);
    return (ushort_t)(u >> 16);
}

// async global->LDS, 16B per lane; LDS dest = wave-uniform base + lane*16
__device__ __forceinline__ void async_copy16(const void* g, void* l) {
    __builtin_amdgcn_global_load_lds(
        (const __attribute__((address_space(1))) void*)g,
        (__attribute__((address_space(3))) void*)l, 16, 0, 0);
}

// ---- kernel 1: RoPE on q,k + cast to bf16 -----------------------------------
// One thread per (t,b,h,j) pair, j in [0,32): handles elements d=j and d=j+32.
__global__ __launch_bounds__(256) void rope_cast_qk(
        const float* __restrict__ q, const float* __restrict__ k,
        ushort_t* __restrict__ qb, ushort_t* __restrict__ kb) {
    int idx  = blockIdx.x * 256 + threadIdx.x;      // [0, T*B*H*32)
    int j    = idx & 31;
    int rest = idx >> 5;                            // t*B*H + b*H + h
    int h    = rest & (H_HEADS - 1);
    int tb   = rest >> 4;                           // t*B + b
    int t    = tb >> 1;
    // inv_freq[j] = 10000^(-j/32) = 2^(-j*log2(10000)/32)
    float inv = exp2f(-(float)j * 0.41524101186092034f);
    float ang = (float)t * inv;
    float s, c;
    sincosf(ang, &s, &c);
    int base = tb * C_DIM + h * DKH + j;
    float q1 = q[base], q2 = q[base + 32];
    float k1 = k[base], k2 = k[base + 32];
    qb[base]      = f2bf(q1 * c - q2 * s);
    qb[base + 32] = f2bf(q2 * c + q1 * s);
    kb[base]      = f2bf(k1 * c - k2 * s);
    kb[base + 32] = f2bf(k2 * c + k1 * s);
}

// ---- kernel 2: generic fp32 -> bf16 cast (vectorized x4) --------------------
__global__ __launch_bounds__(256) void cast_bf16(
        const float* __restrict__ in, ushort_t* __restrict__ out, int n4) {
    int i = blockIdx.x * 256 + threadIdx.x;
    if (i < n4) {
        float4 v = reinterpret_cast<const float4*>(in)[i];
        ushort4 o;
        o.x = f2bf(v.x); o.y = f2bf(v.y); o.z = f2bf(v.z); o.w = f2bf(v.w);
        reinterpret_cast<ushort4*>(out)[i] = o;
    }
}

// ---- kernel 3: NT GEMM  C[m,n] = scale*(sum_k A[m,k]*W[n,k] + bias[n]) ------
// A [M,K] bf16 row-major, W [N,K] bf16 row-major (torch Linear weight layout).
// 128x128 tile, BK=64, 256 thr (4 waves, 2x2), mfma 16x16x32 bf16.
// LDS uses XOR-swizzle (phys_chunk = logical_chunk ^ (row&7)) so both the
// global_load_lds lane order (contiguous 16B/lane) and ds_read_b128 fragment
// reads are conflict-free with no padding.
template <bool BF16_OUT>
__global__ __launch_bounds__(256) void gemm_nt(
        const ushort_t* __restrict__ A, const ushort_t* __restrict__ W,
        const float* __restrict__ bias, void* __restrict__ Cout,
        int M, int N, int K, float scale) {
    __shared__ ushort_t As[128 * 64];
    __shared__ ushort_t Bs[128 * 64];
    const int tid  = threadIdx.x;
    const int lane = tid & 63;
    const int w    = tid >> 6;
    const int wr   = w >> 1, wc = w & 1;
    const int m16  = lane & 15, quad = lane >> 4;
    const int r8   = lane >> 3, c8 = lane & 7;
    const int clog = c8 ^ r8;                  // global k-chunk this lane stages
    const int rowBase = blockIdx.y * 128;
    const int colBase = blockIdx.x * 128;

    f32x4 acc[4][4];
#pragma unroll
    for (int i = 0; i < 4; i++)
#pragma unroll
        for (int j = 0; j < 4; j++) acc[i][j] = (f32x4){0.f, 0.f, 0.f, 0.f};

    for (int kt = 0; kt < K; kt += 64) {
        __syncthreads();   // previous tile's reads complete
#pragma unroll
        for (int i = 0; i < 4; ++i) {
            int R = w * 32 + i * 8;            // 8 rows per wave-instruction
            async_copy16(A + (size_t)(rowBase + R + r8) * K + kt + clog * 8,
                         &As[R * 64]);
            async_copy16(W + (size_t)(colBase + R + r8) * K + kt + clog * 8,
                         &Bs[R * 64]);
        }
        __syncthreads();   // barrier drains vmcnt -> staging visible
#pragma unroll
        for (int ks = 0; ks < 2; ++ks) {
            bf16x8 af[4], bfr[4];
            int lc = ks * 4 + quad;
#pragma unroll
            for (int mi = 0; mi < 4; mi++) {
                int R = wr * 64 + mi * 16 + m16;
                af[mi] = *reinterpret_cast<const bf16x8*>(
                    &As[R * 64 + ((lc ^ (R & 7)) << 3)]);
            }
#pragma unroll
            for (int ni = 0; ni < 4; ni++) {
                int R = wc * 64 + ni * 16 + m16;
                bfr[ni] = *reinterpret_cast<const bf16x8*>(
                    &Bs[R * 64 + ((lc ^ (R & 7)) << 3)]);
            }
#pragma unroll
            for (int mi = 0; mi < 4; mi++)
#pragma unroll
                for (int ni = 0; ni < 4; ni++)
                    acc[mi][ni] = __builtin_amdgcn_mfma_f32_16x16x32_bf16(
                        af[mi], bfr[ni], acc[mi][ni], 0, 0, 0);
        }
    }
    // epilogue: C/D layout col=lane&15, row=quad*4+r
#pragma unroll
    for (int mi = 0; mi < 4; mi++)
#pragma unroll
        for (int ni = 0; ni < 4; ni++)
#pragma unroll
            for (int r = 0; r < 4; r++) {
                int row = rowBase + wr * 64 + mi * 16 + quad * 4 + r;
                int col = colBase + wc * 64 + ni * 16 + m16;
                float v = (acc[mi][ni][r] + bias[col]) * scale;
                if (BF16_OUT)
                    ((ushort_t*)Cout)[(size_t)row * N + col] = f2bf(v);
                else
                    ((float*)Cout)[(size_t)row * N + col] = v;
            }
}

// ---- kernel 4: flash attention ----------------------------------------------
// Grid: (T/64 q-tiles, B*H pairs). Block 256 thr = 4 waves; wave w owns q rows
// [qBase+16w, qBase+16w+16). Keys processed in tiles of 64 with online softmax.
// Qp/Kp/Vp are bf16 [4096,1024], row = t*B+b, col = h*64+dk; Qp pre-scaled 1/8.
__global__ __launch_bounds__(256) void attn(
        const ushort_t* __restrict__ Qp, const ushort_t* __restrict__ Kp,
        const ushort_t* __restrict__ Vp, ushort_t* __restrict__ X) {
    __shared__ ushort_t Qt[64 * 64];
    __shared__ ushort_t Kt[64 * 64];
    __shared__ ushort_t VT[64 * 64];       // V transposed: VT[dk][key]
    __shared__ ushort_t Pt[4][16 * 64];    // per-wave P round-trip (C->A layout)

    const int tid  = threadIdx.x;
    const int lane = tid & 63;
    const int w    = tid >> 6;
    const int m16  = lane & 15, quad = lane >> 4;
    const int r8   = lane >> 3, c8 = lane & 7;
    const int clog = c8 ^ r8;
    const int qBase = blockIdx.x * 64;
    const int pair  = blockIdx.y;          // b*H + h
    const int b = pair >> 4, h = pair & 15;

    // stage Q tile [64 q][64 dk]
#pragma unroll
    for (int i = 0; i < 2; ++i) {
        int R = w * 16 + i * 8;
        async_copy16(Qp + (size_t)((qBase + R + r8) * 2 + b) * C_DIM + h * DKH + clog * 8,
                     &Qt[R * 64]);
    }
    __syncthreads();
    bf16x8 aq[2];  // this wave's Q A-frags (held in regs all kernel)
#pragma unroll
    for (int ks = 0; ks < 2; ks++) {
        int R = w * 16 + m16;
        int lc = ks * 4 + quad;
        aq[ks] = *reinterpret_cast<const bf16x8*>(&Qt[R * 64 + ((lc ^ (R & 7)) << 3)]);
    }

    float mrow[4], lrow[4];
    f32x4 o[4];
#pragma unroll
    for (int r = 0; r < 4; r++) { mrow[r] = -3.0e38f; lrow[r] = 0.f; }
#pragma unroll
    for (int ni = 0; ni < 4; ni++) o[ni] = (f32x4){0.f, 0.f, 0.f, 0.f};

    for (int kt = 0; kt < T_SEQ; kt += 64) {
        __syncthreads();   // prior tile's reads complete
        // stage K tile [64 key][64 dk]
#pragma unroll
        for (int i = 0; i < 2; ++i) {
            int R = w * 16 + i * 8;
            async_copy16(Kp + (size_t)((kt + R + r8) * 2 + b) * C_DIM + h * DKH + clog * 8,
                         &Kt[R * 64]);
        }
        // stage V tile transposed (scalar LDS writes; swizzled like frag reads)
#pragma unroll
        for (int it = 0; it < 2; ++it) {
            int key = it * 32 + (tid >> 3);
            int dkc = (tid & 7) * 8;
            bf16x8 v = *reinterpret_cast<const bf16x8*>(
                Vp + (size_t)((kt + key) * 2 + b) * C_DIM + h * DKH + dkc);
#pragma unroll
            for (int u = 0; u < 8; u++) {
                int dk = dkc + u;
                VT[dk * 64 + ((((key >> 3)) ^ (dk & 7)) << 3) + (key & 7)] =
                    (ushort_t)v[u];
            }
        }
        __syncthreads();
        // S = Q*K^T  (B-frag: n=key=lane&15, k=dk)
        f32x4 s[4];
#pragma unroll
        for (int ni = 0; ni < 4; ni++) s[ni] = (f32x4){0.f, 0.f, 0.f, 0.f};
#pragma unroll
        for (int ks = 0; ks < 2; ks++) {
            int lc = ks * 4 + quad;
#pragma unroll
            for (int ni = 0; ni < 4; ni++) {
                int R = ni * 16 + m16;
                bf16x8 bk = *reinterpret_cast<const bf16x8*>(
                    &Kt[R * 64 + ((lc ^ (R & 7)) << 3)]);
                s[ni] = __builtin_amdgcn_mfma_f32_16x16x32_bf16(aq[ks], bk, s[ni], 0, 0, 0);
            }
        }
        // online softmax: lane holds rows quad*4+r, col = ni*16 + (lane&15)
#pragma unroll
        for (int r = 0; r < 4; r++) {
            float mx = fmaxf(fmaxf(s[0][r], s[1][r]), fmaxf(s[2][r], s[3][r]));
            mx = fmaxf(mx, __shfl_xor(mx, 1));
            mx = fmaxf(mx, __shfl_xor(mx, 2));
            mx = fmaxf(mx, __shfl_xor(mx, 4));
            mx = fmaxf(mx, __shfl_xor(mx, 8));
            float mnew  = fmaxf(mrow[r], mx);
            float alpha = __expf(mrow[r] - mnew);
            float p0 = __expf(s[0][r] - mnew);
            float p1 = __expf(s[1][r] - mnew);
            float p2 = __expf(s[2][r] - mnew);
            float p3 = __expf(s[3][r] - mnew);
            float rs = p0 + p1 + p2 + p3;
            rs += __shfl_xor(rs, 1);
            rs += __shfl_xor(rs, 2);
            rs += __shfl_xor(rs, 4);
            rs += __shfl_xor(rs, 8);
            lrow[r] = lrow[r] * alpha + rs;
            mrow[r] = mnew;
            o[0][r] *= alpha; o[1][r] *= alpha; o[2][r] *= alpha; o[3][r] *= alpha;
            int prow = quad * 4 + r;
            // write P (C-layout) into A-layout LDS tile, swizzled
            {
                int col0 = 0 * 16 + m16;
                Pt[w][prow * 64 + (((col0 >> 3) ^ (prow & 7)) << 3) + (col0 & 7)] = f2bf(p0);
                int col1 = 1 * 16 + m16;
                Pt[w][prow * 64 + (((col1 >> 3) ^ (prow & 7)) << 3) + (col1 & 7)] = f2bf(p1);
                int col2 = 2 * 16 + m16;
                Pt[w][prow * 64 + (((col2 >> 3) ^ (prow & 7)) << 3) + (col2 & 7)] = f2bf(p2);
                int col3 = 3 * 16 + m16;
                Pt[w][prow * 64 + (((col3 >> 3) ^ (prow & 7)) << 3) + (col3 & 7)] = f2bf(p3);
            }
        }
        // wave-internal LDS fence: P writes visible before A-frag reads
        asm volatile("s_waitcnt lgkmcnt(0)" ::: "memory");
        // O += P*V   (A-frag from Pt, B-frag: n=dk=lane&15, k=key via VT)
#pragma unroll
        for (int ks = 0; ks < 2; ks++) {
            int lc = ks * 4 + quad;
            bf16x8 pa = *reinterpret_cast<const bf16x8*>(
                &Pt[w][m16 * 64 + ((lc ^ (m16 & 7)) << 3)]);
#pragma unroll
            for (int ni = 0; ni < 4; ni++) {
                int R = ni * 16 + m16;
                bf16x8 vb = *reinterpret_cast<const bf16x8*>(
                    &VT[R * 64 + ((lc ^ (R & 7)) << 3)]);
                o[ni] = __builtin_amdgcn_mfma_f32_16x16x32_bf16(pa, vb, o[ni], 0, 0, 0);
            }
        }
    }
    // epilogue: normalize and write X bf16 (row = t*B+b, col = h*64+dk)
#pragma unroll
    for (int ni = 0; ni < 4; ni++)
#pragma unroll
        for (int r = 0; r < 4; r++) {
            int t   = qBase + w * 16 + quad * 4 + r;
            int col = h * DKH + ni * 16 + m16;
            X[(size_t)(t * 2 + b) * C_DIM + col] = f2bf(o[ni][r] / lrow[r]);
        }
}

// ---- launch -----------------------------------------------------------------
extern "C" void kernel_launch(void* const* d_in, const int* in_sizes, int n_in,
                              void* d_out, int out_size, void* d_ws, size_t ws_size,
                              hipStream_t stream) {
    const float* query = (const float*)d_in[0];
    const float* key   = (const float*)d_in[1];
    const float* value = (const float*)d_in[2];
    const float* Wq = (const float*)d_in[3];
    const float* bq = (const float*)d_in[4];
    const float* Wk = (const float*)d_in[5];
    const float* bk = (const float*)d_in[6];
    const float* Wv = (const float*)d_in[7];
    const float* bv = (const float*)d_in[8];
    const float* Wo = (const float*)d_in[9];
    const float* bo = (const float*)d_in[10];
    float* out = (float*)d_out;

    // workspace layout (all bf16): 7 x 8MB activations + 4 x 2MB weights = 64MB
    ushort_t* qb  = (ushort_t*)d_ws;
    ushort_t* kb  = qb  + (size_t)M_ROWS * C_DIM;
    ushort_t* vb  = kb  + (size_t)M_ROWS * C_DIM;
    ushort_t* Wqb = vb  + (size_t)M_ROWS * C_DIM;
    ushort_t* Wkb = Wqb + (size_t)C_DIM * C_DIM;
    ushort_t* Wvb = Wkb + (size_t)C_DIM * C_DIM;
    ushort_t* Wob = Wvb + (size_t)C_DIM * C_DIM;
    ushort_t* Qp  = Wob + (size_t)C_DIM * C_DIM;
    ushort_t* Kp  = Qp  + (size_t)M_ROWS * C_DIM;
    ushort_t* Vp  = Kp  + (size_t)M_ROWS * C_DIM;
    ushort_t* Xb  = Vp  + (size_t)M_ROWS * C_DIM;

    // 1) RoPE + casts
    rope_cast_qk<<<(T_SEQ * B_SZ * H_HEADS * 32) / 256, 256, 0, stream>>>(query, key, qb, kb);
    cast_bf16<<<(M_ROWS * C_DIM / 4) / 256, 256, 0, stream>>>(value, vb, M_ROWS * C_DIM / 4);
    cast_bf16<<<(C_DIM * C_DIM / 4) / 256, 256, 0, stream>>>(Wq, Wqb, C_DIM * C_DIM / 4);
    cast_bf16<<<(C_DIM * C_DIM / 4) / 256, 256, 0, stream>>>(Wk, Wkb, C_DIM * C_DIM / 4);
    cast_bf16<<<(C_DIM * C_DIM / 4) / 256, 256, 0, stream>>>(Wv, Wvb, C_DIM * C_DIM / 4);
    cast_bf16<<<(C_DIM * C_DIM / 4) / 256, 256, 0, stream>>>(Wo, Wob, C_DIM * C_DIM / 4);

    // 2) QKV projections (Q pre-scaled by 1/sqrt(64) = 0.125)
    dim3 gg(C_DIM / 128, M_ROWS / 128);
    gemm_nt<true><<<gg, 256, 0, stream>>>(qb, Wqb, bq, Qp, M_ROWS, C_DIM, C_DIM, 0.125f);
    gemm_nt<true><<<gg, 256, 0, stream>>>(kb, Wkb, bk, Kp, M_ROWS, C_DIM, C_DIM, 1.0f);
    gemm_nt<true><<<gg, 256, 0, stream>>>(vb, Wvb, bv, Vp, M_ROWS, C_DIM, C_DIM, 1.0f);

    // 3) flash attention
    attn<<<dim3(T_SEQ / 64, B_SZ * H_HEADS), 256, 0, stream>>>(Qp, Kp, Vp, Xb);

    // 4) output projection -> fp32 d_out ([T,B,C] flat == row-major (t*B+b, c))
    gemm_nt<false><<<gg, 256, 0, stream>>>(Xb, Wob, bo, (void*)out, M_ROWS, C_DIM, C_DIM, 1.0f);
}

// Round 2
// 292.993 us; speedup vs baseline: 1.2950x; 1.2950x over previous
//
#include <hip/hip_runtime.h>
#include <hip/hip_bf16.h>
#include <math.h>

// Problem constants (T=2048, B=2, C=1024, H=16, DK=64)
#define T_SEQ 2048
#define B_SZ 2
#define C_DIM 1024
#define H_HEADS 16
#define DKH 64
#define M_ROWS (T_SEQ * B_SZ)   // 4096 rows in (t,b) order — matches [T,B,C] flat layout

typedef __attribute__((ext_vector_type(8))) short bf16x8;   // 8 bf16 = 4 VGPRs (MFMA A/B frag)
typedef __attribute__((ext_vector_type(4))) float f32x4;    // MFMA C/D frag
typedef unsigned short ushort_t;

// ---- helpers ----------------------------------------------------------------

__device__ __forceinline__ ushort_t f2bf(float f) {
    unsigned u = __float_as_uint(f);
    u += 0x7fffu + ((u >> 16) & 1u);
    return (ushort_t)(u >> 16);
}
__device__ __forceinline__ unsigned pack2bf(float a, float b) {
    return (unsigned)f2bf(a) | ((unsigned)f2bf(b) << 16);
}

__device__ __forceinline__ void async_copy16(const void* g, void* l) {
    __builtin_amdgcn_global_load_lds(
        (const __attribute__((address_space(1))) void*)g,
        (__attribute__((address_space(3))) void*)l, 16, 0, 0);
}

// ---- kernel 1: RoPE on q,k + cast to bf16 (rows t*2+b) ----------------------
__global__ __launch_bounds__(256) void rope_cast_qk(
        const float* __restrict__ q, const float* __restrict__ k,
        ushort_t* __restrict__ qb, ushort_t* __restrict__ kb) {
    int idx  = blockIdx.x * 256 + threadIdx.x;      // [0, T*B*H*32)
    int j    = idx & 31;
    int rest = idx >> 5;                            // t*B*H + b*H + h
    int h    = rest & (H_HEADS - 1);
    int tb   = rest >> 4;                           // t*B + b
    int t    = tb >> 1;
    float inv = exp2f(-(float)j * 0.41524101186092034f);  // 10000^(-j/32)
    float ang = (float)t * inv;
    float s, c;
    sincosf(ang, &s, &c);
    int base = tb * C_DIM + h * DKH + j;
    float q1 = q[base], q2 = q[base + 32];
    float k1 = k[base], k2 = k[base + 32];
    qb[base]      = f2bf(q1 * c - q2 * s);
    qb[base + 32] = f2bf(q2 * c + q1 * s);
    kb[base]      = f2bf(k1 * c - k2 * s);
    kb[base + 32] = f2bf(k2 * c + k1 * s);
}

// ---- kernel 2a: generic fp32 -> bf16 cast (weights) -------------------------
__global__ __launch_bounds__(256) void cast_bf16(
        const float* __restrict__ in, ushort_t* __restrict__ out, int n4) {
    int i = blockIdx.x * 256 + threadIdx.x;
    if (i < n4) {
        float4 v = reinterpret_cast<const float4*>(in)[i];
        ushort4 o;
        o.x = f2bf(v.x); o.y = f2bf(v.y); o.z = f2bf(v.z); o.w = f2bf(v.w);
        reinterpret_cast<ushort4*>(out)[i] = o;
    }
}

// ---- kernel 2b: value cast with row de-interleave: out row = b*T+t ----------
__global__ __launch_bounds__(256) void cast_value_perm(
        const float* __restrict__ in, ushort_t* __restrict__ out) {
    int i   = blockIdx.x * 256 + threadIdx.x;   // float4 index over [4096][256]
    int c4  = i & 255;
    int row = i >> 8;                           // b*2048 + t
    int b   = row >> 11, t = row & 2047;
    float4 v = reinterpret_cast<const float4*>(in)[(t * 2 + b) * 256 + c4];
    ushort4 o;
    o.x = f2bf(v.x); o.y = f2bf(v.y); o.z = f2bf(v.z); o.w = f2bf(v.w);
    reinterpret_cast<ushort4*>(out)[i] = o;
}

// ---- kernel 3: NT GEMM  C[m,n] = scale*(A[m,:]·W[n,:] + bias) --------------
// 128x128 tile, BK=64, 256 thr (4 waves 2x2), mfma 16x16x32 bf16, XOR-swizzled LDS.
template <bool BF16_OUT, bool BIAS_ROW>
__global__ __launch_bounds__(256) void gemm_nt(
        const ushort_t* __restrict__ A, const ushort_t* __restrict__ W,
        const float* __restrict__ bias, void* __restrict__ Cout,
        int M, int N, int K, float scale) {
    __shared__ ushort_t As[128 * 64];
    __shared__ ushort_t Bs[128 * 64];
    const int tid  = threadIdx.x;
    const int lane = tid & 63;
    const int w    = tid >> 6;
    const int wr   = w >> 1, wc = w & 1;
    const int m16  = lane & 15, quad = lane >> 4;
    const int r8   = lane >> 3, c8 = lane & 7;
    const int clog = c8 ^ r8;
    const int rowBase = blockIdx.y * 128;
    const int colBase = blockIdx.x * 128;

    f32x4 acc[4][4];
#pragma unroll
    for (int i = 0; i < 4; i++)
#pragma unroll
        for (int j = 0; j < 4; j++) acc[i][j] = (f32x4){0.f, 0.f, 0.f, 0.f};

    for (int kt = 0; kt < K; kt += 64) {
        __syncthreads();
#pragma unroll
        for (int i = 0; i < 4; ++i) {
            int R = w * 32 + i * 8;
            async_copy16(A + (size_t)(rowBase + R + r8) * K + kt + clog * 8,
                         &As[R * 64]);
            async_copy16(W + (size_t)(colBase + R + r8) * K + kt + clog * 8,
                         &Bs[R * 64]);
        }
        __syncthreads();
#pragma unroll
        for (int ks = 0; ks < 2; ++ks) {
            bf16x8 af[4], bfr[4];
            int lc = ks * 4 + quad;
#pragma unroll
            for (int mi = 0; mi < 4; mi++) {
                int R = wr * 64 + mi * 16 + m16;
                af[mi] = *reinterpret_cast<const bf16x8*>(
                    &As[R * 64 + ((lc ^ (R & 7)) << 3)]);
            }
#pragma unroll
            for (int ni = 0; ni < 4; ni++) {
                int R = wc * 64 + ni * 16 + m16;
                bfr[ni] = *reinterpret_cast<const bf16x8*>(
                    &Bs[R * 64 + ((lc ^ (R & 7)) << 3)]);
            }
#pragma unroll
            for (int mi = 0; mi < 4; mi++)
#pragma unroll
                for (int ni = 0; ni < 4; ni++)
                    acc[mi][ni] = __builtin_amdgcn_mfma_f32_16x16x32_bf16(
                        af[mi], bfr[ni], acc[mi][ni], 0, 0, 0);
        }
    }
#pragma unroll
    for (int mi = 0; mi < 4; mi++)
#pragma unroll
        for (int ni = 0; ni < 4; ni++)
#pragma unroll
            for (int r = 0; r < 4; r++) {
                int row = rowBase + wr * 64 + mi * 16 + quad * 4 + r;
                int col = colBase + wc * 64 + ni * 16 + m16;
                float v = (acc[mi][ni][r] + (BIAS_ROW ? bias[row] : bias[col])) * scale;
                if (BF16_OUT)
                    ((ushort_t*)Cout)[(size_t)row * N + col] = f2bf(v);
                else
                    ((float*)Cout)[(size_t)row * N + col] = v;
            }
}

// ---- kernel 4: flash attention (S^T formulation) ----------------------------
// Grid: (T/64, B*H). 4 waves; wave w owns q rows [qBase+16w, +16).
// S^T = K·Q^T  => C-layout: col(lane&15)=q, row(quad*4+r)=key  => per-lane
// softmax state (m,l scalar). O^T = V^T·P^T accumulated; V^T comes precomputed
// from the swapped V-projection GEMM (VTg[c_out][b*T+t]).
__global__ __launch_bounds__(256) void attn(
        const ushort_t* __restrict__ Qp, const ushort_t* __restrict__ Kp,
        const ushort_t* __restrict__ VTg, ushort_t* __restrict__ X) {
    __shared__ ushort_t Qt[64 * 64];   // Q staging; reused as per-wave P/O tile
    __shared__ ushort_t Kt[64 * 64];
    __shared__ ushort_t VT[64 * 64];

    const int tid  = threadIdx.x;
    const int lane = tid & 63;
    const int w    = tid >> 6;
    const int m16  = lane & 15, quad = lane >> 4;
    const int r8   = lane >> 3, c8 = lane & 7;
    const int clog = c8 ^ r8;
    const int qBase = blockIdx.x * 64;
    const int pair  = blockIdx.y;          // b*H + h
    const int b = pair >> 4, h = pair & 15;

    // stage Q tile [64 q][64 dk]
#pragma unroll
    for (int i = 0; i < 2; ++i) {
        int R = w * 16 + i * 8;
        async_copy16(Qp + (size_t)((qBase + R + r8) * 2 + b) * C_DIM + h * DKH + clog * 8,
                     &Qt[R * 64]);
    }
    __syncthreads();
    bf16x8 aq[2];  // Q B-frags: lane holds q = w*16+m16
#pragma unroll
    for (int ks = 0; ks < 2; ks++) {
        int R = w * 16 + m16;
        aq[ks] = *reinterpret_cast<const bf16x8*>(
            &Qt[R * 64 + (((ks * 4 + quad) ^ (m16 & 7)) << 3)]);
    }
    asm volatile("s_waitcnt lgkmcnt(0)" ::: "memory");  // aq in regs
    __syncthreads();                                    // before Qt reuse as P

    ushort_t* Pw = &Qt[w * 16 * 64];   // wave-private [16 q][64 key], XOR-swizzled

    float mrun = -3.0e38f, lrun = 0.f;  // per-lane: q = w*16+m16
    f32x4 o[4];                          // O^T: o[mi][r] = O^T[dk=mi*16+quad*4+r][q]
#pragma unroll
    for (int mi = 0; mi < 4; mi++) o[mi] = (f32x4){0.f, 0.f, 0.f, 0.f};

    for (int kt = 0; kt < T_SEQ; kt += 64) {
        __syncthreads();
        // stage K tile [64 key][64 dk] and V^T tile [64 dk][64 key]
#pragma unroll
        for (int i = 0; i < 2; ++i) {
            int R = w * 16 + i * 8;
            async_copy16(Kp + (size_t)((kt + R + r8) * 2 + b) * C_DIM + h * DKH + clog * 8,
                         &Kt[R * 64]);
            async_copy16(VTg + (size_t)(h * DKH + R + r8) * M_ROWS + b * T_SEQ + kt + clog * 8,
                         &VT[R * 64]);
        }
        __syncthreads();

        // S^T = K·Q^T : s[ni][r] = S^T[key=ni*16+quad*4+r][q]
        f32x4 s[4];
#pragma unroll
        for (int ni = 0; ni < 4; ni++) s[ni] = (f32x4){0.f, 0.f, 0.f, 0.f};
#pragma unroll
        for (int ks = 0; ks < 2; ks++) {
#pragma unroll
            for (int ni = 0; ni < 4; ni++) {
                int R = ni * 16 + m16;
                bf16x8 kf = *reinterpret_cast<const bf16x8*>(
                    &Kt[R * 64 + (((ks * 4 + quad) ^ (m16 & 7)) << 3)]);
                s[ni] = __builtin_amdgcn_mfma_f32_16x16x32_bf16(kf, aq[ks], s[ni], 0, 0, 0);
            }
        }

        // online softmax: all 16 values in this lane share q; reduce over quads
        float tm = s[0][0];
#pragma unroll
        for (int ni = 0; ni < 4; ni++)
#pragma unroll
            for (int r = 0; r < 4; r++) tm = fmaxf(tm, s[ni][r]);
        tm = fmaxf(tm, __shfl_xor(tm, 16));
        tm = fmaxf(tm, __shfl_xor(tm, 32));
        float mnew  = fmaxf(mrun, tm);
        float alpha = __expf(mrun - mnew);
        mrun = mnew;
        float p[4][4];
        float rs = 0.f;
#pragma unroll
        for (int ni = 0; ni < 4; ni++)
#pragma unroll
            for (int r = 0; r < 4; r++) {
                p[ni][r] = __expf(s[ni][r] - mnew);
                rs += p[ni][r];
            }
        rs += __shfl_xor(rs, 16);
        rs += __shfl_xor(rs, 32);
        lrun = lrun * alpha + rs;
#pragma unroll
        for (int mi = 0; mi < 4; mi++)
#pragma unroll
            for (int r = 0; r < 4; r++) o[mi][r] *= alpha;

        // write P (bf16) to wave-private LDS [q][key], XOR-swizzled, b64 stores
#pragma unroll
        for (int ni = 0; ni < 4; ni++) {
            uint2 pv;
            pv.x = pack2bf(p[ni][0], p[ni][1]);
            pv.y = pack2bf(p[ni][2], p[ni][3]);
            int chunk = ((ni * 2 + (quad >> 1)) ^ (m16 & 7));
            reinterpret_cast<uint2*>(Pw)[m16 * 16 + chunk * 2 + (quad & 1)] = pv;
        }
        asm volatile("s_waitcnt lgkmcnt(0)" ::: "memory");

        // O^T += V^T·P^T : A=V^T rows dk, B=P rows q
#pragma unroll
        for (int ks = 0; ks < 2; ks++) {
            bf16x8 pf = *reinterpret_cast<const bf16x8*>(
                &Pw[m16 * 64 + (((ks * 4 + quad) ^ (m16 & 7)) << 3)]);
#pragma unroll
            for (int mi = 0; mi < 4; mi++) {
                int R = mi * 16 + m16;
                bf16x8 vf = *reinterpret_cast<const bf16x8*>(
                    &VT[R * 64 + (((ks * 4 + quad) ^ (m16 & 7)) << 3)]);
                o[mi] = __builtin_amdgcn_mfma_f32_16x16x32_bf16(vf, pf, o[mi], 0, 0, 0);
            }
        }
    }

    // epilogue: normalize, transpose via wave-private LDS, coalesced X stores
    float invl = 1.0f / lrun;
#pragma unroll
    for (int mi = 0; mi < 4; mi++) {
        uint2 ov;
        ov.x = pack2bf(o[mi][0] * invl, o[mi][1] * invl);
        ov.y = pack2bf(o[mi][2] * invl, o[mi][3] * invl);
        int chunk = ((mi * 2 + (quad >> 1)) ^ (m16 & 7));
        reinterpret_cast<uint2*>(Pw)[m16 * 16 + chunk * 2 + (quad & 1)] = ov;
    }
    asm volatile("s_waitcnt lgkmcnt(0)" ::: "memory");
#pragma unroll
    for (int it = 0; it < 2; ++it) {
        int ql = lane >> 2;
        int c  = (lane & 3) + 4 * it;
        bf16x8 vo = *reinterpret_cast<const bf16x8*>(
            &Pw[ql * 64 + ((c ^ (ql & 7)) << 3)]);
        int t = qBase + w * 16 + ql;
        *reinterpret_cast<bf16x8*>(
            &X[(size_t)(t * 2 + b) * C_DIM + h * DKH + c * 8]) = vo;
    }
}

// ---- launch -----------------------------------------------------------------
extern "C" void kernel_launch(void* const* d_in, const int* in_sizes, int n_in,
                              void* d_out, int out_size, void* d_ws, size_t ws_size,
                              hipStream_t stream) {
    const float* query = (const float*)d_in[0];
    const float* key   = (const float*)d_in[1];
    const float* value = (const float*)d_in[2];
    const float* Wq = (const float*)d_in[3];
    const float* bq = (const float*)d_in[4];
    const float* Wk = (const float*)d_in[5];
    const float* bk = (const float*)d_in[6];
    const float* Wv = (const float*)d_in[7];
    const float* bv = (const float*)d_in[8];
    const float* Wo = (const float*)d_in[9];
    const float* bo = (const float*)d_in[10];
    float* out = (float*)d_out;

    ushort_t* qb  = (ushort_t*)d_ws;                    // [4096][1024] rows t*2+b
    ushort_t* kb  = qb  + (size_t)M_ROWS * C_DIM;       // [4096][1024] rows t*2+b
    ushort_t* vb2 = kb  + (size_t)M_ROWS * C_DIM;       // [4096][1024] rows b*T+t
    ushort_t* Wqb = vb2 + (size_t)M_ROWS * C_DIM;
    ushort_t* Wkb = Wqb + (size_t)C_DIM * C_DIM;
    ushort_t* Wvb = Wkb + (size_t)C_DIM * C_DIM;
    ushort_t* Wob = Wvb + (size_t)C_DIM * C_DIM;
    ushort_t* Qp  = Wob + (size_t)C_DIM * C_DIM;        // [4096][1024] rows t*2+b
    ushort_t* Kp  = Qp  + (size_t)M_ROWS * C_DIM;       // [4096][1024] rows t*2+b
    ushort_t* VTg = Kp  + (size_t)M_ROWS * C_DIM;       // [1024][4096]: [c_out][b*T+t]
    ushort_t* Xb  = VTg + (size_t)M_ROWS * C_DIM;       // [4096][1024] rows t*2+b

    // 1) RoPE + casts
    rope_cast_qk<<<(T_SEQ * B_SZ * H_HEADS * 32) / 256, 256, 0, stream>>>(query, key, qb, kb);
    cast_value_perm<<<(M_ROWS * C_DIM / 4) / 256, 256, 0, stream>>>(value, vb2);
    cast_bf16<<<(C_DIM * C_DIM / 4) / 256, 256, 0, stream>>>(Wq, Wqb, C_DIM * C_DIM / 4);
    cast_bf16<<<(C_DIM * C_DIM / 4) / 256, 256, 0, stream>>>(Wk, Wkb, C_DIM * C_DIM / 4);
    cast_bf16<<<(C_DIM * C_DIM / 4) / 256, 256, 0, stream>>>(Wv, Wvb, C_DIM * C_DIM / 4);
    cast_bf16<<<(C_DIM * C_DIM / 4) / 256, 256, 0, stream>>>(Wo, Wob, C_DIM * C_DIM / 4);

    // 2) projections: Q (pre-scaled 1/8), K natural; V swapped => V^T directly
    dim3 gg(C_DIM / 128, M_ROWS / 128);
    gemm_nt<true, false><<<gg, 256, 0, stream>>>(qb, Wqb, bq, Qp, M_ROWS, C_DIM, C_DIM, 0.125f);
    gemm_nt<true, false><<<gg, 256, 0, stream>>>(kb, Wkb, bk, Kp, M_ROWS, C_DIM, C_DIM, 1.0f);
    dim3 gv(M_ROWS / 128, C_DIM / 128);
    gemm_nt<true, true><<<gv, 256, 0, stream>>>(Wvb, vb2, bv, VTg, C_DIM, M_ROWS, C_DIM, 1.0f);

    // 3) flash attention (S^T / O^T formulation)
    attn<<<dim3(T_SEQ / 64, B_SZ * H_HEADS), 256, 0, stream>>>(Qp, Kp, VTg, Xb);

    // 4) output projection -> fp32 d_out
    gemm_nt<false, false><<<gg, 256, 0, stream>>>(Xb, Wob, bo, (void*)out, M_ROWS, C_DIM, C_DIM, 1.0f);
}